// Round 9
// baseline (277.139 us; speedup 1.0000x reference)
//
#include <hip/hip_runtime.h>
#include <hip/hip_bf16.h>
#include <cstddef>

// Problem dims (fixed): B=8, T=200, U=50, U1=51, H=320, V=1024.
#define Bdim 8
#define Tdim 200
#define Udim 50
#define U1dim 51
#define Hdim 320
#define Vdim 1024
#define NEGV -1.0e30f
#define LOG2E 1.4426950408889634f
#define LN2f  0.6931471805599453f

using short8 = __attribute__((ext_vector_type(8))) short;
using f32x4  = __attribute__((ext_vector_type(4))) float;

static __device__ __forceinline__ ushort f2bf(float x) {
    __hip_bfloat16 h = __float2bfloat16(x);
    return *reinterpret_cast<ushort*>(&h);
}
static __device__ __forceinline__ int pack2(float a, float b) {
    return (int)f2bf(a) | ((int)f2bf(b) << 16);
}

// ---------------------------------------------------------------------------
// Fused-weight prep (unchanged).
// ---------------------------------------------------------------------------
__global__ __launch_bounds__(256) void fuse_weights(
    const float* __restrict__ W_enc, const float* __restrict__ W_ff_enc,
    const float* __restrict__ W_pred, const float* __restrict__ W_ff_pred,
    const float* __restrict__ b_enc, const float* __restrict__ b_pred,
    const float* __restrict__ b_ff,
    ushort* __restrict__ Wfe_t, ushort* __restrict__ Wfp_t,
    float* __restrict__ cvec, float* __restrict__ dvec)
{
    const int tid = threadIdx.x;
    if (blockIdx.y == 16) {                 // fused bias vectors
        if (blockIdx.x > 1) return;
        const bool e = (blockIdx.x == 0);
        const float* bv = e ? b_enc : b_pred;
        const float* Wf = e ? W_ff_enc : W_ff_pred;
        float* ovec = e ? cvec : dvec;
        const int v = tid * 4;
        float4 acc = make_float4(0.f, 0.f, 0.f, 0.f);
        for (int p = 0; p < Hdim; ++p) {
            float s = bv[p];
            float4 w = *(const float4*)&Wf[(size_t)p * Vdim + v];
            acc.x += s * w.x; acc.y += s * w.y; acc.z += s * w.z; acc.w += s * w.w;
        }
        if (e) {
            float4 bf = *(const float4*)&b_ff[v];
            acc.x += bf.x; acc.y += bf.y; acc.z += bf.z; acc.w += bf.w;
        }
        *(float4*)&ovec[v] = acc;
        return;
    }

    const bool e = (blockIdx.x < 5);
    const float* A  = e ? W_ff_enc : W_ff_pred;   // [320][1024] f32, used transposed
    const float* Bm = e ? W_enc    : W_pred;      // [320][320]  f32, direct
    ushort* Cout    = e ? Wfe_t    : Wfp_t;       // [1024][320] bf16
    const int n0 = (blockIdx.x % 5) * 64;         // j
    const int m0 = blockIdx.y * 64;               // v

    __shared__ short As[64][40];   // As[v][p]
    __shared__ short Bs[64][40];   // Bs[j][p]

    const int ar = tid >> 3;            // p row 0..31
    const int ac = (tid & 7) * 8;       // v base 0..56
    const int br = tid >> 2;            // j row 0..63
    const int bc = (tid & 3) * 8;       // p base 0..24

    const int lane = tid & 63;
    const int wave = tid >> 6;
    const int wr = wave >> 1, wc = wave & 1;
    const int lrow = lane & 15;
    const int kg = (lane >> 4) * 8;

    f32x4 acc[2][2] = {};

    for (int k0 = 0; k0 < Hdim; k0 += 32) {
        float4 a0 = *(const float4*)&A[(size_t)(k0 + ar) * Vdim + m0 + ac];
        float4 a1 = *(const float4*)&A[(size_t)(k0 + ar) * Vdim + m0 + ac + 4];
        As[ac + 0][ar] = (short)f2bf(a0.x);
        As[ac + 1][ar] = (short)f2bf(a0.y);
        As[ac + 2][ar] = (short)f2bf(a0.z);
        As[ac + 3][ar] = (short)f2bf(a0.w);
        As[ac + 4][ar] = (short)f2bf(a1.x);
        As[ac + 5][ar] = (short)f2bf(a1.y);
        As[ac + 6][ar] = (short)f2bf(a1.z);
        As[ac + 7][ar] = (short)f2bf(a1.w);
        float4 w0 = *(const float4*)&Bm[(size_t)(n0 + br) * Hdim + k0 + bc];
        float4 w1 = *(const float4*)&Bm[(size_t)(n0 + br) * Hdim + k0 + bc + 4];
        int4 bp = make_int4(pack2(w0.x, w0.y), pack2(w0.z, w0.w),
                            pack2(w1.x, w1.y), pack2(w1.z, w1.w));
        *(int4*)&Bs[br][bc] = bp;
        __syncthreads();

        short8 fa0 = *(const short8*)&As[wr * 32 + lrow][kg];
        short8 fa1 = *(const short8*)&As[wr * 32 + 16 + lrow][kg];
        short8 fb0 = *(const short8*)&Bs[wc * 32 + lrow][kg];
        short8 fb1 = *(const short8*)&Bs[wc * 32 + 16 + lrow][kg];
        acc[0][0] = __builtin_amdgcn_mfma_f32_16x16x32_bf16(fa0, fb0, acc[0][0], 0, 0, 0);
        acc[0][1] = __builtin_amdgcn_mfma_f32_16x16x32_bf16(fa0, fb1, acc[0][1], 0, 0, 0);
        acc[1][0] = __builtin_amdgcn_mfma_f32_16x16x32_bf16(fa1, fb0, acc[1][0], 0, 0, 0);
        acc[1][1] = __builtin_amdgcn_mfma_f32_16x16x32_bf16(fa1, fb1, acc[1][1], 0, 0, 0);
        __syncthreads();
    }

    #pragma unroll
    for (int fm = 0; fm < 2; ++fm) {
        #pragma unroll
        for (int fn = 0; fn < 2; ++fn) {
            int col = n0 + wc * 32 + fn * 16 + lrow;
            int r0 = m0 + wr * 32 + fm * 16 + (lane >> 4) * 4;
            #pragma unroll
            for (int r = 0; r < 4; ++r)
                Cout[(size_t)(r0 + r) * Hdim + col] = f2bf(acc[fm][fn][r]);
        }
    }
}

// ---------------------------------------------------------------------------
// Main GEMM (unchanged).
// ---------------------------------------------------------------------------
__global__ __launch_bounds__(256) void main_gemm(
    const float* __restrict__ enc, const float* __restrict__ pred,
    const ushort* __restrict__ Wfe_t, const ushort* __restrict__ Wfp_t,
    const float* __restrict__ cvec, const float* __restrict__ dvec,
    float* __restrict__ enc_part, float* __restrict__ pred_part)
{
    const bool e = (blockIdx.y < 25);
    const float*  A    = e ? enc : pred;
    const ushort* Bt   = e ? Wfe_t : Wfp_t;
    const float*  bias = e ? cvec : dvec;
    float*        C    = e ? enc_part : pred_part;
    const int M  = e ? (Bdim * Tdim) : (Bdim * U1dim);
    const int m0 = (e ? blockIdx.y : blockIdx.y - 25) * 64;
    const int n0 = blockIdx.x * 64;

    __shared__ short As[64][40];
    __shared__ short Bs[64][40];
    const int tid = threadIdx.x;
    const int sr = tid >> 2;
    const int sc = (tid & 3) * 8;

    const int lane = tid & 63;
    const int wave = tid >> 6;
    const int wr = wave >> 1, wc = wave & 1;
    const int lrow = lane & 15;
    const int kg = (lane >> 4) * 8;

    f32x4 acc[2][2] = {};

    for (int k0 = 0; k0 < Hdim; k0 += 32) {
        int4 av = make_int4(0, 0, 0, 0);
        if (m0 + sr < M) {
            float4 x0 = *(const float4*)&A[(size_t)(m0 + sr) * Hdim + k0 + sc];
            float4 x1 = *(const float4*)&A[(size_t)(m0 + sr) * Hdim + k0 + sc + 4];
            av = make_int4(pack2(x0.x, x0.y), pack2(x0.z, x0.w),
                           pack2(x1.x, x1.y), pack2(x1.z, x1.w));
        }
        *(int4*)&As[sr][sc] = av;
        *(int4*)&Bs[sr][sc] = *(const int4*)&Bt[(size_t)(n0 + sr) * Hdim + k0 + sc];
        __syncthreads();

        short8 fa0 = *(const short8*)&As[wr * 32 + lrow][kg];
        short8 fa1 = *(const short8*)&As[wr * 32 + 16 + lrow][kg];
        short8 fb0 = *(const short8*)&Bs[wc * 32 + lrow][kg];
        short8 fb1 = *(const short8*)&Bs[wc * 32 + 16 + lrow][kg];
        acc[0][0] = __builtin_amdgcn_mfma_f32_16x16x32_bf16(fa0, fb0, acc[0][0], 0, 0, 0);
        acc[0][1] = __builtin_amdgcn_mfma_f32_16x16x32_bf16(fa0, fb1, acc[0][1], 0, 0, 0);
        acc[1][0] = __builtin_amdgcn_mfma_f32_16x16x32_bf16(fa1, fb0, acc[1][0], 0, 0, 0);
        acc[1][1] = __builtin_amdgcn_mfma_f32_16x16x32_bf16(fa1, fb1, acc[1][1], 0, 0, 0);
        __syncthreads();
    }

    #pragma unroll
    for (int fm = 0; fm < 2; ++fm) {
        #pragma unroll
        for (int fn = 0; fn < 2; ++fn) {
            int col = n0 + wc * 32 + fn * 16 + lrow;
            int r0 = m0 + wr * 32 + fm * 16 + (lane >> 4) * 4;
            float bv = bias[col];
            #pragma unroll
            for (int r = 0; r < 4; ++r) {
                int row = r0 + r;
                if (row < M)
                    C[(size_t)row * Vdim + col] = acc[fm][fn][r] + bv;
            }
        }
    }
}

// ---------------------------------------------------------------------------
// lp_kernel: log-softmax stats ONLY (no logits stream). Block = (b, chunk of
// 16 t's), 4 waves x 4 t's; lane owns v = lane*16..+15 in registers.
// ---------------------------------------------------------------------------
__global__ __launch_bounds__(256) void lp_kernel(
    const float* __restrict__ enc_part, const float* __restrict__ pred_part,
    const int* __restrict__ ys, float* __restrict__ out,
    float* __restrict__ lp_blank, float* __restrict__ lp_label)
{
    const int b = blockIdx.x;          // 0..7
    const int chunk = blockIdx.y;      // 0..12
    const int tid = threadIdx.x;
    const int lane = tid & 63;
    const int wave = tid >> 6;
    if (b == 0 && chunk == 0 && tid == 0) out[0] = 0.f;  // loss accumulator
    const int t0 = chunk * 16 + wave * 4;
    if (t0 >= Tdim) return;

    float4 e0[4], e1[4], e2[4], e3[4];
    #pragma unroll
    for (int j = 0; j < 4; ++j) {
        const float* Erow = enc_part + (size_t)(b * Tdim + t0 + j) * Vdim + lane * 16;
        e0[j] = *(const float4*)(Erow + 0);
        e1[j] = *(const float4*)(Erow + 4);
        e2[j] = *(const float4*)(Erow + 8);
        e3[j] = *(const float4*)(Erow + 12);
    }

    const float* Pbase = pred_part + (size_t)b * U1dim * Vdim + lane * 16;

    for (int u = 0; u < U1dim; ++u) {
        const float* P = Pbase + (size_t)u * Vdim;
        float4 p0 = *(const float4*)(P + 0);
        float4 p1 = *(const float4*)(P + 4);
        float4 p2 = *(const float4*)(P + 8);
        float4 p3 = *(const float4*)(P + 12);

        const int vlab = (u < Udim) ? ys[b * Udim + u] : 0;
        const int idx = vlab & 15;
        const int src = vlab >> 4;

        #pragma unroll
        for (int j = 0; j < 4; ++j) {
            float xa[16];
            xa[0] = e0[j].x + p0.x;  xa[1] = e0[j].y + p0.y;
            xa[2] = e0[j].z + p0.z;  xa[3] = e0[j].w + p0.w;
            xa[4] = e1[j].x + p1.x;  xa[5] = e1[j].y + p1.y;
            xa[6] = e1[j].z + p1.z;  xa[7] = e1[j].w + p1.w;
            xa[8] = e2[j].x + p2.x;  xa[9] = e2[j].y + p2.y;
            xa[10]= e2[j].z + p2.z;  xa[11]= e2[j].w + p2.w;
            xa[12]= e3[j].x + p3.x;  xa[13]= e3[j].y + p3.y;
            xa[14]= e3[j].z + p3.z;  xa[15]= e3[j].w + p3.w;

            // lse without max-subtraction (|x| small, safe in f32)
            float s = 0.f;
            #pragma unroll
            for (int i = 0; i < 16; ++i) s += __expf(xa[i]);
            #pragma unroll
            for (int off = 32; off >= 1; off >>= 1) s += __shfl_xor(s, off);
            float lse = __logf(s);

            float cand = xa[0];
            #pragma unroll
            for (int i = 1; i < 16; ++i) if (i == idx) cand = xa[i];
            float lab = __shfl(cand, src);

            if (lane == 0) {
                const int bt = b * Tdim + t0 + j;
                lp_blank[(size_t)bt * U1dim + u] = xa[0] - lse;
                if (u < Udim) lp_label[(size_t)bt * Udim + u] = lab - lse;
            }
        }
    }
}

// ---------------------------------------------------------------------------
// logits_kernel: PURE streaming writer — no exp/log, no reductions, no lp.
// Block = (b, chunk of 4 t's); each wave owns one t, loops all u.
// Stores shuffle-realigned full float4 on the global 16B grid (base d_out+1).
// ---------------------------------------------------------------------------
__global__ __launch_bounds__(256) void logits_kernel(
    const float* __restrict__ enc_part, const float* __restrict__ pred_part,
    float* __restrict__ out)
{
    const int b = blockIdx.x;          // 0..7
    const int chunk = blockIdx.y;      // 0..49
    const int tid = threadIdx.x;
    const int lane = tid & 63;
    const int wave = tid >> 6;
    const int t = chunk * 4 + wave;    // 0..199
    const int bt = b * Tdim + t;

    const float* Erow = enc_part + (size_t)bt * Vdim + lane * 16;
    float4 e0 = *(const float4*)(Erow + 0);
    float4 e1 = *(const float4*)(Erow + 4);
    float4 e2 = *(const float4*)(Erow + 8);
    float4 e3 = *(const float4*)(Erow + 12);

    const float* Pbase = pred_part + (size_t)b * U1dim * Vdim + lane * 16;
    float* region = out + 1 + (size_t)bt * U1dim * Vdim;

    float4 p0, p1, p2, p3;
    {
        p0 = *(const float4*)(Pbase + 0);
        p1 = *(const float4*)(Pbase + 4);
        p2 = *(const float4*)(Pbase + 8);
        p3 = *(const float4*)(Pbase + 12);
    }

    for (int u = 0; u < U1dim; ++u) {
        float4 q0, q1, q2, q3;
        if (u + 1 < U1dim) {
            const float* P = Pbase + (size_t)(u + 1) * Vdim;
            q0 = *(const float4*)(P + 0);
            q1 = *(const float4*)(P + 4);
            q2 = *(const float4*)(P + 8);
            q3 = *(const float4*)(P + 12);
        }

        float xa[16];
        xa[0]=e0.x+p0.x;  xa[1]=e0.y+p0.y;  xa[2]=e0.z+p0.z;  xa[3]=e0.w+p0.w;
        xa[4]=e1.x+p1.x;  xa[5]=e1.y+p1.y;  xa[6]=e1.z+p1.z;  xa[7]=e1.w+p1.w;
        xa[8]=e2.x+p2.x;  xa[9]=e2.y+p2.y;  xa[10]=e2.z+p2.z; xa[11]=e2.w+p2.w;
        xa[12]=e3.x+p3.x; xa[13]=e3.y+p3.y; xa[14]=e3.z+p3.z; xa[15]=e3.w+p3.w;

        float nx0 = __shfl_down(xa[0], 1);
        float nx1 = __shfl_down(xa[1], 1);
        float nx2 = __shfl_down(xa[2], 1);

        float* rowb = region + (size_t)u * Vdim;   // ≡1 mod 4 floats
        float* W = rowb + 3 + lane * 16;           // 16B-aligned
        *(float4*)(W + 0) = make_float4(xa[3],  xa[4],  xa[5],  xa[6]);
        *(float4*)(W + 4) = make_float4(xa[7],  xa[8],  xa[9],  xa[10]);
        *(float4*)(W + 8) = make_float4(xa[11], xa[12], xa[13], xa[14]);
        if (lane < 63) {
            *(float4*)(W + 12) = make_float4(xa[15], nx0, nx1, nx2);
        } else {
            rowb[1023] = xa[15];
        }
        if (lane == 0) {
            rowb[0] = xa[0];
            rowb[1] = xa[1];
            rowb[2] = xa[2];
        }

        p0 = q0; p1 = q1; p2 = q2; p3 = q3;
    }
}

// ---------------------------------------------------------------------------
// RNN-T alpha wavefront over anti-diagonals (base-2 domain, unchanged).
// ---------------------------------------------------------------------------
__global__ __launch_bounds__(256) void alpha_kernel(
    const float* __restrict__ lp_blank, const float* __restrict__ lp_label,
    const int* __restrict__ ylen, float* __restrict__ out)
{
    __shared__ float s_bl[U1dim * Tdim];   // [u][t], scaled by LOG2E
    __shared__ float s_lab[Udim * Tdim];   // [u][t], scaled by LOG2E
    const int b = blockIdx.x;
    const int tid = threadIdx.x;
    const float* gb = lp_blank + (size_t)b * Tdim * U1dim;
    const float* gl = lp_label + (size_t)b * Tdim * Udim;
    for (int i = tid; i < Tdim * U1dim; i += 256) {
        int t = i / U1dim, u = i % U1dim;
        s_bl[u * Tdim + t] = gb[i] * LOG2E;
    }
    for (int i = tid; i < Tdim * Udim; i += 256) {
        int t = i / Udim, u = i % Udim;
        s_lab[u * Tdim + t] = gl[i] * LOG2E;
    }
    __syncthreads();

    if (tid < 64) {
        const int u = tid;
        float cur = NEGV;
        for (int d = 0; d < Tdim + U1dim - 1; ++d) {
            float left = __shfl_up(cur, 1);
            int t = d - u;
            if (u < U1dim && t >= 0 && t < Tdim) {
                float h = (t >= 1) ? cur + s_bl[u * Tdim + (t - 1)] : NEGV;
                float g = (u >= 1) ? left + s_lab[(u - 1) * Tdim + t] : NEGV;
                float mx = fmaxf(h, g);
                float nv = mx + __log2f(1.0f + exp2f(-fabsf(h - g)));
                if (d == 0) nv = 0.f;
                cur = nv;
            }
        }
        const int L = ylen[b];
        if (u == L)
            atomicAdd(out, -(cur + s_bl[L * Tdim + (Tdim - 1)]) * (LN2f / Bdim));
    }
}

// ---------------------------------------------------------------------------
extern "C" void kernel_launch(void* const* d_in, const int* in_sizes, int n_in,
                              void* d_out, int out_size, void* d_ws, size_t ws_size,
                              hipStream_t stream)
{
    const float* enc      = (const float*)d_in[0];   // (8,200,320)
    const float* pred     = (const float*)d_in[1];   // (8,51,320)
    const int*   ys       = (const int*)d_in[4];     // (8,50)
    const int*   ylen     = (const int*)d_in[5];     // (8,)
    const float* W_enc    = (const float*)d_in[6];   // (320,320)
    const float* b_enc    = (const float*)d_in[7];   // (320,)
    const float* W_pred   = (const float*)d_in[8];
    const float* b_pred   = (const float*)d_in[9];
    const float* W_ff_enc = (const float*)d_in[10];  // (320,1024)
    const float* W_ff_pred= (const float*)d_in[11];
    const float* b_ff     = (const float*)d_in[12];  // (1024,)
    float* out = (float*)d_out;
    char* ws = (char*)d_ws;

    // -------- workspace layout (byte offsets) --------
    float*  enc_part  = (float*) (ws + 0);          // 1600*1024 f32 = 6,553,600 B
    float*  pred_part = (float*) (ws + 6553600);    //  408*1024 f32 = 1,671,168 B
    ushort* Wfe_t     = (ushort*)(ws + 8224768);    // 1024*320 bf16 =   655,360 B
    ushort* Wfp_t     = (ushort*)(ws + 8880128);    //   655,360 B
    float*  cvec      = (float*) (ws + 9535488);    //     4,096 B
    float*  dvec      = (float*) (ws + 9539584);    //     4,096 B
    float*  lp_blank  = (float*) (ws + 9543680);    //   326,400 B
    float*  lp_label  = (float*) (ws + 9870080);    //   320,000 B  (end 10,190,080)

    dim3 blk(256);
    fuse_weights<<<dim3(10, 17), blk, 0, stream>>>(
        W_enc, W_ff_enc, W_pred, W_ff_pred, b_enc, b_pred, b_ff,
        Wfe_t, Wfp_t, cvec, dvec);
    main_gemm<<<dim3(16, 32), blk, 0, stream>>>(
        enc, pred, Wfe_t, Wfp_t, cvec, dvec, enc_part, pred_part);
    lp_kernel<<<dim3(Bdim, 13), blk, 0, stream>>>(
        enc_part, pred_part, ys, out, lp_blank, lp_label);
    alpha_kernel<<<dim3(Bdim), blk, 0, stream>>>(lp_blank, lp_label, ylen, out);
    logits_kernel<<<dim3(Bdim, 50), blk, 0, stream>>>(
        enc_part, pred_part, out);
}

// Round 10
// 201.188 us; speedup vs baseline: 1.3775x; 1.3775x over previous
//
#include <hip/hip_runtime.h>
#include <hip/hip_bf16.h>
#include <cstddef>

// Problem dims (fixed): B=8, T=200, U=50, U1=51, H=320, V=1024.
#define Bdim 8
#define Tdim 200
#define Udim 50
#define U1dim 51
#define Hdim 320
#define Vdim 1024
#define NEGV -1.0e30f
#define LOG2E 1.4426950408889634f
#define LN2f  0.6931471805599453f

using short8 = __attribute__((ext_vector_type(8))) short;
using f32x4  = __attribute__((ext_vector_type(4))) float;

static __device__ __forceinline__ ushort f2bf(float x) {
    __hip_bfloat16 h = __float2bfloat16(x);
    return *reinterpret_cast<ushort*>(&h);
}
static __device__ __forceinline__ int pack2(float a, float b) {
    return (int)f2bf(a) | ((int)f2bf(b) << 16);
}

// ---------------------------------------------------------------------------
// Fused-weight GEMM: Wfe_t[v][j] = sum_p W_ff[p][v] * W[j][p]  (bf16 out).
// grid (10, 16): x<5 enc / x>=5 pred.
// ---------------------------------------------------------------------------
__global__ __launch_bounds__(256) void fuse_weights(
    const float* __restrict__ W_enc, const float* __restrict__ W_ff_enc,
    const float* __restrict__ W_pred, const float* __restrict__ W_ff_pred,
    ushort* __restrict__ Wfe_t, ushort* __restrict__ Wfp_t)
{
    const int tid = threadIdx.x;
    const bool e = (blockIdx.x < 5);
    const float* A  = e ? W_ff_enc : W_ff_pred;   // [320][1024] f32, used transposed
    const float* Bm = e ? W_enc    : W_pred;      // [320][320]  f32, direct
    ushort* Cout    = e ? Wfe_t    : Wfp_t;       // [1024][320] bf16
    const int n0 = (blockIdx.x % 5) * 64;         // j
    const int m0 = blockIdx.y * 64;               // v

    __shared__ short As[64][40];   // As[v][p]
    __shared__ short Bs[64][40];   // Bs[j][p]

    const int ar = tid >> 3;            // p row 0..31
    const int ac = (tid & 7) * 8;       // v base 0..56
    const int br = tid >> 2;            // j row 0..63
    const int bc = (tid & 3) * 8;       // p base 0..24

    const int lane = tid & 63;
    const int wave = tid >> 6;
    const int wr = wave >> 1, wc = wave & 1;
    const int lrow = lane & 15;
    const int kg = (lane >> 4) * 8;

    f32x4 acc[2][2] = {};

    for (int k0 = 0; k0 < Hdim; k0 += 32) {
        float4 a0 = *(const float4*)&A[(size_t)(k0 + ar) * Vdim + m0 + ac];
        float4 a1 = *(const float4*)&A[(size_t)(k0 + ar) * Vdim + m0 + ac + 4];
        As[ac + 0][ar] = (short)f2bf(a0.x);
        As[ac + 1][ar] = (short)f2bf(a0.y);
        As[ac + 2][ar] = (short)f2bf(a0.z);
        As[ac + 3][ar] = (short)f2bf(a0.w);
        As[ac + 4][ar] = (short)f2bf(a1.x);
        As[ac + 5][ar] = (short)f2bf(a1.y);
        As[ac + 6][ar] = (short)f2bf(a1.z);
        As[ac + 7][ar] = (short)f2bf(a1.w);
        float4 w0 = *(const float4*)&Bm[(size_t)(n0 + br) * Hdim + k0 + bc];
        float4 w1 = *(const float4*)&Bm[(size_t)(n0 + br) * Hdim + k0 + bc + 4];
        int4 bp = make_int4(pack2(w0.x, w0.y), pack2(w0.z, w0.w),
                            pack2(w1.x, w1.y), pack2(w1.z, w1.w));
        *(int4*)&Bs[br][bc] = bp;
        __syncthreads();

        short8 fa0 = *(const short8*)&As[wr * 32 + lrow][kg];
        short8 fa1 = *(const short8*)&As[wr * 32 + 16 + lrow][kg];
        short8 fb0 = *(const short8*)&Bs[wc * 32 + lrow][kg];
        short8 fb1 = *(const short8*)&Bs[wc * 32 + 16 + lrow][kg];
        acc[0][0] = __builtin_amdgcn_mfma_f32_16x16x32_bf16(fa0, fb0, acc[0][0], 0, 0, 0);
        acc[0][1] = __builtin_amdgcn_mfma_f32_16x16x32_bf16(fa0, fb1, acc[0][1], 0, 0, 0);
        acc[1][0] = __builtin_amdgcn_mfma_f32_16x16x32_bf16(fa1, fb0, acc[1][0], 0, 0, 0);
        acc[1][1] = __builtin_amdgcn_mfma_f32_16x16x32_bf16(fa1, fb1, acc[1][1], 0, 0, 0);
        __syncthreads();
    }

    #pragma unroll
    for (int fm = 0; fm < 2; ++fm) {
        #pragma unroll
        for (int fn = 0; fn < 2; ++fn) {
            int col = n0 + wc * 32 + fn * 16 + lrow;
            int r0 = m0 + wr * 32 + fm * 16 + (lane >> 4) * 4;
            #pragma unroll
            for (int r = 0; r < 4; ++r)
                Cout[(size_t)(r0 + r) * Hdim + col] = f2bf(acc[fm][fn][r]);
        }
    }
}

// ---------------------------------------------------------------------------
// bias_vec: cvec[v] = b_enc @ W_ff_enc + b_ff ; dvec[v] = b_pred @ W_ff_pred.
// 2 blocks x 1024 threads, one v per thread, unrolled p-loop (pipelined loads).
// ---------------------------------------------------------------------------
__global__ __launch_bounds__(1024) void bias_vec(
    const float* __restrict__ b_enc, const float* __restrict__ W_ff_enc,
    const float* __restrict__ b_pred, const float* __restrict__ W_ff_pred,
    const float* __restrict__ b_ff,
    float* __restrict__ cvec, float* __restrict__ dvec)
{
    const bool e = (blockIdx.x == 0);
    const float* bv = e ? b_enc : b_pred;
    const float* Wf = e ? W_ff_enc : W_ff_pred;
    float* ovec = e ? cvec : dvec;
    const int v = threadIdx.x;
    float acc = 0.f;
    #pragma unroll 8
    for (int p = 0; p < Hdim; ++p)
        acc += bv[p] * Wf[(size_t)p * Vdim + v];
    if (e) acc += b_ff[v];
    ovec[v] = acc;
}

// ---------------------------------------------------------------------------
// Main GEMM (unchanged).
// ---------------------------------------------------------------------------
__global__ __launch_bounds__(256) void main_gemm(
    const float* __restrict__ enc, const float* __restrict__ pred,
    const ushort* __restrict__ Wfe_t, const ushort* __restrict__ Wfp_t,
    const float* __restrict__ cvec, const float* __restrict__ dvec,
    float* __restrict__ enc_part, float* __restrict__ pred_part)
{
    const bool e = (blockIdx.y < 25);
    const float*  A    = e ? enc : pred;
    const ushort* Bt   = e ? Wfe_t : Wfp_t;
    const float*  bias = e ? cvec : dvec;
    float*        C    = e ? enc_part : pred_part;
    const int M  = e ? (Bdim * Tdim) : (Bdim * U1dim);
    const int m0 = (e ? blockIdx.y : blockIdx.y - 25) * 64;
    const int n0 = blockIdx.x * 64;

    __shared__ short As[64][40];
    __shared__ short Bs[64][40];
    const int tid = threadIdx.x;
    const int sr = tid >> 2;
    const int sc = (tid & 3) * 8;

    const int lane = tid & 63;
    const int wave = tid >> 6;
    const int wr = wave >> 1, wc = wave & 1;
    const int lrow = lane & 15;
    const int kg = (lane >> 4) * 8;

    f32x4 acc[2][2] = {};

    for (int k0 = 0; k0 < Hdim; k0 += 32) {
        int4 av = make_int4(0, 0, 0, 0);
        if (m0 + sr < M) {
            float4 x0 = *(const float4*)&A[(size_t)(m0 + sr) * Hdim + k0 + sc];
            float4 x1 = *(const float4*)&A[(size_t)(m0 + sr) * Hdim + k0 + sc + 4];
            av = make_int4(pack2(x0.x, x0.y), pack2(x0.z, x0.w),
                           pack2(x1.x, x1.y), pack2(x1.z, x1.w));
        }
        *(int4*)&As[sr][sc] = av;
        *(int4*)&Bs[sr][sc] = *(const int4*)&Bt[(size_t)(n0 + sr) * Hdim + k0 + sc];
        __syncthreads();

        short8 fa0 = *(const short8*)&As[wr * 32 + lrow][kg];
        short8 fa1 = *(const short8*)&As[wr * 32 + 16 + lrow][kg];
        short8 fb0 = *(const short8*)&Bs[wc * 32 + lrow][kg];
        short8 fb1 = *(const short8*)&Bs[wc * 32 + 16 + lrow][kg];
        acc[0][0] = __builtin_amdgcn_mfma_f32_16x16x32_bf16(fa0, fb0, acc[0][0], 0, 0, 0);
        acc[0][1] = __builtin_amdgcn_mfma_f32_16x16x32_bf16(fa0, fb1, acc[0][1], 0, 0, 0);
        acc[1][0] = __builtin_amdgcn_mfma_f32_16x16x32_bf16(fa1, fb0, acc[1][0], 0, 0, 0);
        acc[1][1] = __builtin_amdgcn_mfma_f32_16x16x32_bf16(fa1, fb1, acc[1][1], 0, 0, 0);
        __syncthreads();
    }

    #pragma unroll
    for (int fm = 0; fm < 2; ++fm) {
        #pragma unroll
        for (int fn = 0; fn < 2; ++fn) {
            int col = n0 + wc * 32 + fn * 16 + lrow;
            int r0 = m0 + wr * 32 + fm * 16 + (lane >> 4) * 4;
            float bv = bias[col];
            #pragma unroll
            for (int r = 0; r < 4; ++r) {
                int row = r0 + r;
                if (row < M)
                    C[(size_t)row * Vdim + col] = acc[fm][fn][r] + bv;
            }
        }
    }
}

// ---------------------------------------------------------------------------
// joint_lse: fused logits stream + log-softmax stats.
// Block = (b, t-oct), 512 threads = 8 waves, wave w owns t = oct*8 + w.
// pred[b] staged in LDS in 4 chunks of <=13 rows (53 KB), chunk-major float4
// layout (lane reads ds_read_b128 at <=8-way conflict). Per-u body has NO
// global loads -> store stream never stalls on vmem load-waits.
// enc row lives in registers. Stores shuffle-realigned to the 16B grid.
// ---------------------------------------------------------------------------
#define CHUNK 13
__global__ __launch_bounds__(512) void joint_lse(
    const float* __restrict__ enc_part, const float* __restrict__ pred_part,
    const int* __restrict__ ys, float* __restrict__ out,
    float* __restrict__ lp_blank, float* __restrict__ lp_label)
{
    __shared__ float S[CHUNK * Vdim];   // 53,248 B
    const int b = blockIdx.x;           // 0..7
    const int oct = blockIdx.y;         // 0..24
    const int tid = threadIdx.x;
    const int lane = tid & 63;
    const int wave = tid >> 6;          // 0..7
    const int t = oct * 8 + wave;       // 0..199
    const int bt = b * Tdim + t;
    if (b == 0 && oct == 0 && tid == 0) out[0] = 0.f;   // loss accumulator

    // enc row in registers
    const float* Erow = enc_part + (size_t)bt * Vdim + lane * 16;
    float4 e0 = *(const float4*)(Erow + 0);
    float4 e1 = *(const float4*)(Erow + 4);
    float4 e2 = *(const float4*)(Erow + 8);
    float4 e3 = *(const float4*)(Erow + 12);

    const float* Pb = pred_part + (size_t)b * U1dim * Vdim;
    float* region = out + 1 + (size_t)bt * U1dim * Vdim;

    for (int c = 0; c < 4; ++c) {
        const int u0 = c * CHUNK;
        const int rows = (u0 + CHUNK <= U1dim) ? CHUNK : (U1dim - u0);
        const int nf4 = rows * 256;                 // float4s to stage
        __syncthreads();                            // all waves done with prev chunk
        for (int idx = tid; idx < nf4; idx += 512) {
            const int ul = idx >> 8;                // local row
            const int j  = idx & 255;               // float4 within row
            float4 vv = *(const float4*)&Pb[(size_t)(u0 + ul) * Vdim + j * 4];
            // chunk-major: dst dword = ul*1024 + ((j&3)*64 + (j>>2))*4
            *(float4*)&S[ul * Vdim + ((j & 3) * 64 + (j >> 2)) * 4] = vv;
        }
        __syncthreads();

        for (int ul = 0; ul < rows; ++ul) {
            const int u = u0 + ul;
            const float* Sr = &S[ul * Vdim];
            float4 p0 = *(const float4*)&Sr[(0 * 64 + lane) * 4];
            float4 p1 = *(const float4*)&Sr[(1 * 64 + lane) * 4];
            float4 p2 = *(const float4*)&Sr[(2 * 64 + lane) * 4];
            float4 p3 = *(const float4*)&Sr[(3 * 64 + lane) * 4];

            float xa[16];
            xa[0]=e0.x+p0.x;  xa[1]=e0.y+p0.y;  xa[2]=e0.z+p0.z;  xa[3]=e0.w+p0.w;
            xa[4]=e1.x+p1.x;  xa[5]=e1.y+p1.y;  xa[6]=e1.z+p1.z;  xa[7]=e1.w+p1.w;
            xa[8]=e2.x+p2.x;  xa[9]=e2.y+p2.y;  xa[10]=e2.z+p2.z; xa[11]=e2.w+p2.w;
            xa[12]=e3.x+p3.x; xa[13]=e3.y+p3.y; xa[14]=e3.z+p3.z; xa[15]=e3.w+p3.w;

            // realign to global 16B grid (logits base = d_out+1)
            float nx0 = __shfl_down(xa[0], 1);
            float nx1 = __shfl_down(xa[1], 1);
            float nx2 = __shfl_down(xa[2], 1);

            float* rowb = region + (size_t)u * Vdim;   // index ≡ 1 (mod 4)
            float* W = rowb + 3 + lane * 16;           // 16B-aligned
            *(float4*)(W + 0) = make_float4(xa[3],  xa[4],  xa[5],  xa[6]);
            *(float4*)(W + 4) = make_float4(xa[7],  xa[8],  xa[9],  xa[10]);
            *(float4*)(W + 8) = make_float4(xa[11], xa[12], xa[13], xa[14]);
            if (lane < 63) {
                *(float4*)(W + 12) = make_float4(xa[15], nx0, nx1, nx2);
            } else {
                rowb[1023] = xa[15];
            }
            if (lane == 0) {
                rowb[0] = xa[0];
                rowb[1] = xa[1];
                rowb[2] = xa[2];
            }

            // lse without max-subtraction (|x| small, safe in f32)
            float s = 0.f;
            #pragma unroll
            for (int i = 0; i < 16; ++i) s += __expf(xa[i]);
            #pragma unroll
            for (int off = 32; off >= 1; off >>= 1) s += __shfl_xor(s, off);
            float lse = __logf(s);

            const int vlab = (u < Udim) ? ys[b * Udim + u] : 0;
            const int idx = vlab & 15;
            const int src = vlab >> 4;
            float cand = xa[0];
            #pragma unroll
            for (int i = 1; i < 16; ++i) if (i == idx) cand = xa[i];
            float lab = __shfl(cand, src);

            if (lane == 0) {
                lp_blank[(size_t)bt * U1dim + u] = xa[0] - lse;
                if (u < Udim) lp_label[(size_t)bt * Udim + u] = lab - lse;
            }
        }
    }
}

// ---------------------------------------------------------------------------
// RNN-T alpha wavefront over anti-diagonals (base-2 domain, unchanged).
// ---------------------------------------------------------------------------
__global__ __launch_bounds__(256) void alpha_kernel(
    const float* __restrict__ lp_blank, const float* __restrict__ lp_label,
    const int* __restrict__ ylen, float* __restrict__ out)
{
    __shared__ float s_bl[U1dim * Tdim];   // [u][t], scaled by LOG2E
    __shared__ float s_lab[Udim * Tdim];   // [u][t], scaled by LOG2E
    const int b = blockIdx.x;
    const int tid = threadIdx.x;
    const float* gb = lp_blank + (size_t)b * Tdim * U1dim;
    const float* gl = lp_label + (size_t)b * Tdim * Udim;
    for (int i = tid; i < Tdim * U1dim; i += 256) {
        int t = i / U1dim, u = i % U1dim;
        s_bl[u * Tdim + t] = gb[i] * LOG2E;
    }
    for (int i = tid; i < Tdim * Udim; i += 256) {
        int t = i / Udim, u = i % Udim;
        s_lab[u * Tdim + t] = gl[i] * LOG2E;
    }
    __syncthreads();

    if (tid < 64) {
        const int u = tid;
        float cur = NEGV;
        for (int d = 0; d < Tdim + U1dim - 1; ++d) {
            float left = __shfl_up(cur, 1);
            int t = d - u;
            if (u < U1dim && t >= 0 && t < Tdim) {
                float h = (t >= 1) ? cur + s_bl[u * Tdim + (t - 1)] : NEGV;
                float g = (u >= 1) ? left + s_lab[(u - 1) * Tdim + t] : NEGV;
                float mx = fmaxf(h, g);
                float nv = mx + __log2f(1.0f + exp2f(-fabsf(h - g)));
                if (d == 0) nv = 0.f;
                cur = nv;
            }
        }
        const int L = ylen[b];
        if (u == L)
            atomicAdd(out, -(cur + s_bl[L * Tdim + (Tdim - 1)]) * (LN2f / Bdim));
    }
}

// ---------------------------------------------------------------------------
extern "C" void kernel_launch(void* const* d_in, const int* in_sizes, int n_in,
                              void* d_out, int out_size, void* d_ws, size_t ws_size,
                              hipStream_t stream)
{
    const float* enc      = (const float*)d_in[0];   // (8,200,320)
    const float* pred     = (const float*)d_in[1];   // (8,51,320)
    const int*   ys       = (const int*)d_in[4];     // (8,50)
    const int*   ylen     = (const int*)d_in[5];     // (8,)
    const float* W_enc    = (const float*)d_in[6];   // (320,320)
    const float* b_enc    = (const float*)d_in[7];   // (320,)
    const float* W_pred   = (const float*)d_in[8];
    const float* b_pred   = (const float*)d_in[9];
    const float* W_ff_enc = (const float*)d_in[10];  // (320,1024)
    const float* W_ff_pred= (const float*)d_in[11];
    const float* b_ff     = (const float*)d_in[12];  // (1024,)
    float* out = (float*)d_out;
    char* ws = (char*)d_ws;

    // -------- workspace layout (byte offsets) --------
    float*  enc_part  = (float*) (ws + 0);          // 1600*1024 f32 = 6,553,600 B
    float*  pred_part = (float*) (ws + 6553600);    //  408*1024 f32 = 1,671,168 B
    ushort* Wfe_t     = (ushort*)(ws + 8224768);    // 1024*320 bf16 =   655,360 B
    ushort* Wfp_t     = (ushort*)(ws + 8880128);    //   655,360 B
    float*  cvec      = (float*) (ws + 9535488);    //     4,096 B
    float*  dvec      = (float*) (ws + 9539584);    //     4,096 B
    float*  lp_blank  = (float*) (ws + 9543680);    //   326,400 B
    float*  lp_label  = (float*) (ws + 9870080);    //   320,000 B  (end 10,190,080)

    fuse_weights<<<dim3(10, 16), dim3(256), 0, stream>>>(
        W_enc, W_ff_enc, W_pred, W_ff_pred, Wfe_t, Wfp_t);
    bias_vec<<<dim3(2), dim3(1024), 0, stream>>>(
        b_enc, W_ff_enc, b_pred, W_ff_pred, b_ff, cvec, dvec);
    main_gemm<<<dim3(16, 32), dim3(256), 0, stream>>>(
        enc, pred, Wfe_t, Wfp_t, cvec, dvec, enc_part, pred_part);
    joint_lse<<<dim3(Bdim, 25), dim3(512), 0, stream>>>(
        enc_part, pred_part, ys, out, lp_blank, lp_label);
    alpha_kernel<<<dim3(Bdim), dim3(256), 0, stream>>>(
        lp_blank, lp_label, ylen, out);
}